// Round 1
// 33906.296 us; speedup vs baseline: 2.1363x; 2.1363x over previous
//
#include <hip/hip_runtime.h>

// LSTMGapFiller R2: decoder -> bf16x3 split MFMA (v_mfma_f32_16x16x32_bf16).
// fp32 x = hi+lo bf16; z = hi*hi + lo*hi + hi*lo accumulated in fp32 AGPRs
// (~2^-17 rel err, below current fp32 reorder noise). Weights packed once into
// fragment-linear order; h stored as bf16 hi/lo; c stays fp32. Context layers
// stay fp32 this round (+ XCD-locality swizzle on ctx_l1).

#define L_SEQ 100
#define BATCH 1024
#define HCTX 256
#define HG 512
#define TDEC 256

typedef __attribute__((ext_vector_type(8))) short bf16x8;
typedef __attribute__((ext_vector_type(4))) float f32x4;

__device__ __forceinline__ float sigf(float x){ return 1.0f/(1.0f+expf(-x)); }
__device__ __forceinline__ unsigned short f2bf(float x){
  unsigned int u = __float_as_uint(x);
  return (unsigned short)((u + 0x7fffu + ((u>>16)&1u)) >> 16);   // RNE
}
__device__ __forceinline__ float bf2f(unsigned short h){
  return __uint_as_float(((unsigned int)h)<<16);
}

// src[J][K] -> dst[K][J]
__global__ void transpose_k(const float* __restrict__ src, float* __restrict__ dst,
                            int J, int K){
  int idx = blockIdx.x*blockDim.x + threadIdx.x;
  if (idx < J*K){
    int j = idx / K, k = idx % K;
    dst[k*J + j] = src[idx];
  }
}

// Pack W[G][K] (fp32, row-major) into MFMA-fragment-linear bf16 hi/lo.
// Element (gt, kt, lane, j) = W[gt*16 + (lane&15)][kt*32 + (lane>>4)*8 + j],
// stored at ((gt*KTtot + kt0+ktl)*64 + lane)*8 + j  -> per-lane 16B contiguous.
__global__ void pack_w(const float* __restrict__ W, int G, int K, int KTtot, int kt0,
                       unsigned short* __restrict__ hi, unsigned short* __restrict__ lo){
  int idx = blockIdx.x*blockDim.x + threadIdx.x;
  int kt_n = K/32;
  int total = (G/16)*kt_n*64;
  if (idx >= total) return;
  int lane = idx & 63;
  int ktl = (idx>>6) % kt_n;
  int gt  = (idx>>6) / kt_n;
  int g = gt*16 + (lane & 15);
  int k = ktl*32 + (lane>>4)*8;
  const float* src = W + (size_t)g*K + k;
  size_t dst = (((size_t)gt*KTtot + (kt0 + ktl))*64 + lane)*8;
  #pragma unroll
  for (int j=0;j<8;j++){
    float x = src[j];
    unsigned short h = f2bf(x);
    hi[dst+j] = h;
    lo[dst+j] = f2bf(x - bf2f(h));
  }
}

// precompute embedding projections (vocab=5):
// ectx0[d][v][j] = ctx0_b[d][j] + emb[v] . ctx0_Wih[d][j]   (j<1024)
// egen0[v][j]    = gen0_b[j]    + emb[v] . gen0_Wih[j]      (j<2048)
__global__ void embprep(const float* __restrict__ emb,
                        const float* __restrict__ c0Wih, const float* __restrict__ c0b,
                        const float* __restrict__ g0Wih, const float* __restrict__ g0b,
                        float* __restrict__ ectx0, float* __restrict__ egen0){
  int idx = blockIdx.x*blockDim.x + threadIdx.x;
  if (idx < 2*5*1024){
    int d = idx / 5120;
    int v = (idx / 1024) % 5;
    int j = idx % 1024;
    const float* w = c0Wih + ((size_t)d*1024 + j)*64;
    const float* e = emb + v*64;
    float s = c0b[d*1024 + j];
    #pragma unroll
    for (int k=0;k<64;k++) s += e[k]*w[k];
    ectx0[idx] = s;
  } else if (idx < 2*5*1024 + 5*2048){
    int i2 = idx - 10240;
    int v = i2 / 2048;
    int j = i2 % 2048;
    const float* w = g0Wih + (size_t)j*64;
    const float* e = emb + v*64;
    float s = g0b[j];
    #pragma unroll
    for (int k=0;k<64;k++) s += e[k]*w[k];
    egen0[i2] = s;
  }
}

// ctx layer 0: grid (128, 2), block 512 (u = tid&255, eh = tid>>8 owns 4 elems).
__global__ void ctx_l0(const int* __restrict__ toks,
                       const float* __restrict__ ectx0,
                       const float* __restrict__ whhT,
                       float* __restrict__ y0){
  const int dir = blockIdx.y;
  const int e0 = blockIdx.x * 8;
  const int u = threadIdx.x & 255;
  const int eh = threadIdx.x >> 8;
  __shared__ float hs[8][256];
  __shared__ float cs[8][256];
  #pragma unroll
  for (int j=0;j<4;j++){ hs[eh*4+j][u]=0.f; cs[eh*4+j][u]=0.f; }
  __syncthreads();
  const float* wbase = whhT + (size_t)dir*256*1024;
  for (int s=0;s<L_SEQ;s++){
    const int t = dir ? (L_SEQ-1-s) : s;
    float acc[4][4];
    #pragma unroll
    for (int j=0;j<4;j++){
      int e = eh*4+j;
      int tk = toks[(e0+e)*L_SEQ + t];
      const float* ep = ectx0 + ((size_t)dir*5 + tk)*1024 + u;
      acc[j][0]=ep[0]; acc[j][1]=ep[256]; acc[j][2]=ep[512]; acc[j][3]=ep[768];
    }
    for (int k=0;k<256;k++){
      const float* w = wbase + k*1024 + u;
      float w0=w[0], w1=w[256], w2=w[512], w3=w[768];
      #pragma unroll
      for (int j=0;j<4;j++){
        float hv = hs[eh*4+j][k];
        acc[j][0]+=hv*w0; acc[j][1]+=hv*w1; acc[j][2]+=hv*w2; acc[j][3]+=hv*w3;
      }
    }
    __syncthreads();
    #pragma unroll
    for (int j=0;j<4;j++){
      int e = eh*4+j;
      float ig = sigf(acc[j][0]);
      float fg = sigf(acc[j][1]);
      float gg = tanhf(acc[j][2]);
      float og = sigf(acc[j][3]);
      float c = fg*cs[e][u] + ig*gg;
      float h = og*tanhf(c);
      cs[e][u]=c; hs[e][u]=h;
      y0[((size_t)t*BATCH + (e0+e))*512 + dir*256 + u] = h;
    }
    __syncthreads();
  }
}

// ctx layer 1. 1D grid of 256 blocks, dir/e0 swizzled so each direction's 3MB
// weight set stays on half the XCDs (id%8 in 0..3 -> dir0, 4..7 -> dir1).
__global__ void ctx_l1(const float* __restrict__ y0,
                       const float* __restrict__ wihT,
                       const float* __restrict__ whhT,
                       const float* __restrict__ bias,
                       float* __restrict__ finals, int t_store){
  const int id = blockIdx.x;
  const int dir = (id >> 2) & 1;
  const int e0 = (((id >> 3) << 2) | (id & 3)) * 8;
  const int u = threadIdx.x & 255;
  const int eh = threadIdx.x >> 8;
  __shared__ float hs[8][256];
  __shared__ float cs[8][256];
  __shared__ float xs[8][512];
  #pragma unroll
  for (int j=0;j<4;j++){ hs[eh*4+j][u]=0.f; cs[eh*4+j][u]=0.f; }
  __syncthreads();
  const float* wi = wihT + (size_t)dir*512*1024;
  const float* wh = whhT + (size_t)dir*256*1024;
  const float b0 = bias[dir*1024 + u];
  const float b1 = bias[dir*1024 + 256 + u];
  const float b2 = bias[dir*1024 + 512 + u];
  const float b3 = bias[dir*1024 + 768 + u];
  for (int s=0;s<L_SEQ;s++){
    const int t = dir ? (L_SEQ-1-s) : s;
    const float* xsrc = y0 + ((size_t)t*BATCH + e0)*512;
    for (int i=threadIdx.x;i<8*512;i+=512) ((float*)xs)[i] = xsrc[i];
    __syncthreads();
    float acc[4][4];
    #pragma unroll
    for (int j=0;j<4;j++){ acc[j][0]=b0; acc[j][1]=b1; acc[j][2]=b2; acc[j][3]=b3; }
    for (int k=0;k<512;k++){
      const float* w = wi + k*1024 + u;
      float w0=w[0], w1=w[256], w2=w[512], w3=w[768];
      #pragma unroll
      for (int j=0;j<4;j++){
        float xv = xs[eh*4+j][k];
        acc[j][0]+=xv*w0; acc[j][1]+=xv*w1; acc[j][2]+=xv*w2; acc[j][3]+=xv*w3;
      }
    }
    for (int k=0;k<256;k++){
      const float* w = wh + k*1024 + u;
      float w0=w[0], w1=w[256], w2=w[512], w3=w[768];
      #pragma unroll
      for (int j=0;j<4;j++){
        float hv = hs[eh*4+j][k];
        acc[j][0]+=hv*w0; acc[j][1]+=hv*w1; acc[j][2]+=hv*w2; acc[j][3]+=hv*w3;
      }
    }
    __syncthreads();
    #pragma unroll
    for (int j=0;j<4;j++){
      int e = eh*4+j;
      float ig = sigf(acc[j][0]);
      float fg = sigf(acc[j][1]);
      float gg = tanhf(acc[j][2]);
      float og = sigf(acc[j][3]);
      float c = fg*cs[e][u] + ig*gg;
      float h = og*tanhf(c);
      cs[e][u]=c; hs[e][u]=h;
      if (t == t_store) finals[(size_t)(e0+e)*512 + dir*256 + u] = h;
    }
    __syncthreads();
  }
}

__global__ void combine_init2(const float* __restrict__ lf, const float* __restrict__ rf,
                              unsigned short* __restrict__ h0h, unsigned short* __restrict__ h0l,
                              unsigned short* __restrict__ h1h, unsigned short* __restrict__ h1l,
                              float* __restrict__ c0, float* __restrict__ c1,
                              int* __restrict__ tok){
  int i = blockIdx.x*blockDim.x + threadIdx.x;
  if (i < BATCH*HG){
    float v = 0.5f*(lf[i]+rf[i]);
    unsigned short h = f2bf(v);
    unsigned short l = f2bf(v - bf2f(h));
    h0h[i]=h; h0l[i]=l; h1h[i]=h; h1l[i]=l;
    c0[i]=0.f; c1[i]=0.f;
  }
  if (i < BATCH) tok[i]=0;
}

// decoder layer 0 (MFMA): 256 blocks x 512 thr (8 waves). Block = 64 elems x 32
// units (x4 gates). Wave (wm 0..3, wu 0..1) = 1 M-tile x 4 gate col-tiles.
// by = bid%16 so same-weight-slice blocks share an XCD L2.
__global__ void __launch_bounds__(512,2) dec_l0_mfma(
    const int* __restrict__ tok,
    const float* __restrict__ egen0,
    const unsigned short* __restrict__ wh, const unsigned short* __restrict__ wl,
    const unsigned short* __restrict__ hih, const unsigned short* __restrict__ hil,
    unsigned short* __restrict__ hoh, unsigned short* __restrict__ hol,
    float* __restrict__ cst)
{
  const int bid = blockIdx.x;
  const int by = bid & 15;            // unit-group (32 units)
  const int bx = bid >> 4;            // elem-group (64 elems)
  const int e0 = bx * 64;
  const int lane = threadIdx.x & 63;
  const int w = threadIdx.x >> 6;
  const int wm = w & 3;
  const int wu = w >> 2;
  const int ut = by*2 + wu;           // global unit-tile 0..31
  const int lo16 = lane & 15;
  const int kgrp = lane >> 4;
  const int row = e0 + wm*16 + lo16;

  const unsigned short* pah = hih + (size_t)row*512 + kgrp*8;
  const unsigned short* pal = hil + (size_t)row*512 + kgrp*8;
  const unsigned short* pb[8];
  #pragma unroll
  for (int q=0;q<4;q++){
    size_t off = ((size_t)(q*32+ut)*16*64 + lane)*8;   // KT=16
    pb[q]   = wh + off;
    pb[q+4] = wl + off;
  }
  f32x4 zero = {0.f,0.f,0.f,0.f};
  f32x4 acc[4] = {zero, zero, zero, zero};
  #pragma unroll 2
  for (int ks=0; ks<16; ks++){
    bf16x8 ah = *(const bf16x8*)(pah + ks*32);
    bf16x8 al = *(const bf16x8*)(pal + ks*32);
    #pragma unroll
    for (int q=0;q<4;q++){
      bf16x8 bh = *(const bf16x8*)(pb[q]   + ks*512);
      bf16x8 bl = *(const bf16x8*)(pb[q+4] + ks*512);
      acc[q] = __builtin_amdgcn_mfma_f32_16x16x32_bf16(ah, bh, acc[q], 0,0,0);
      acc[q] = __builtin_amdgcn_mfma_f32_16x16x32_bf16(al, bh, acc[q], 0,0,0);
      acc[q] = __builtin_amdgcn_mfma_f32_16x16x32_bf16(ah, bl, acc[q], 0,0,0);
    }
  }
  const int u = ut*16 + lo16;
  const int r0 = e0 + wm*16 + kgrp*4;   // D row = 4*(lane>>4)+reg (m89 layout)
  #pragma unroll
  for (int r=0;r<4;r++){
    const int e = r0 + r;
    const int tk = tok[e];
    const float* ep = egen0 + (size_t)tk*2048 + u;
    float zi = acc[0][r] + ep[0];
    float zf = acc[1][r] + ep[512];
    float zg = acc[2][r] + ep[1024];
    float zo = acc[3][r] + ep[1536];
    const size_t idx = (size_t)e*512 + u;
    float c = sigf(zf)*cst[idx] + sigf(zi)*tanhf(zg);
    float h = sigf(zo)*tanhf(c);
    cst[idx] = c;
    unsigned short hb = f2bf(h);
    hoh[idx] = hb;
    hol[idx] = f2bf(h - bf2f(hb));
  }
}

// decoder layer 1 (MFMA): K=1024 = [x(=h0out) ; h1prev]. Same geometry, KT=32.
__global__ void __launch_bounds__(512,2) dec_l1_mfma(
    const unsigned short* __restrict__ xh, const unsigned short* __restrict__ xl,
    const unsigned short* __restrict__ wh, const unsigned short* __restrict__ wl,
    const float* __restrict__ bias,
    const unsigned short* __restrict__ hih, const unsigned short* __restrict__ hil,
    unsigned short* __restrict__ hoh, unsigned short* __restrict__ hol,
    float* __restrict__ cst)
{
  const int bid = blockIdx.x;
  const int by = bid & 15;
  const int bx = bid >> 4;
  const int e0 = bx * 64;
  const int lane = threadIdx.x & 63;
  const int w = threadIdx.x >> 6;
  const int wm = w & 3;
  const int wu = w >> 2;
  const int ut = by*2 + wu;
  const int lo16 = lane & 15;
  const int kgrp = lane >> 4;
  const int row = e0 + wm*16 + lo16;

  const unsigned short* pxh = xh  + (size_t)row*512 + kgrp*8;
  const unsigned short* pxl = xl  + (size_t)row*512 + kgrp*8;
  const unsigned short* pah = hih + (size_t)row*512 + kgrp*8;
  const unsigned short* pal = hil + (size_t)row*512 + kgrp*8;
  const unsigned short* pb[8];
  #pragma unroll
  for (int q=0;q<4;q++){
    size_t off = ((size_t)(q*32+ut)*32*64 + lane)*8;   // KT=32
    pb[q]   = wh + off;
    pb[q+4] = wl + off;
  }
  f32x4 zero = {0.f,0.f,0.f,0.f};
  f32x4 acc[4] = {zero, zero, zero, zero};
  #pragma unroll 2
  for (int ks=0; ks<16; ks++){          // k 0..511 : x
    bf16x8 ah = *(const bf16x8*)(pxh + ks*32);
    bf16x8 al = *(const bf16x8*)(pxl + ks*32);
    #pragma unroll
    for (int q=0;q<4;q++){
      bf16x8 bh = *(const bf16x8*)(pb[q]   + ks*512);
      bf16x8 bl = *(const bf16x8*)(pb[q+4] + ks*512);
      acc[q] = __builtin_amdgcn_mfma_f32_16x16x32_bf16(ah, bh, acc[q], 0,0,0);
      acc[q] = __builtin_amdgcn_mfma_f32_16x16x32_bf16(al, bh, acc[q], 0,0,0);
      acc[q] = __builtin_amdgcn_mfma_f32_16x16x32_bf16(ah, bl, acc[q], 0,0,0);
    }
  }
  #pragma unroll 2
  for (int ks=16; ks<32; ks++){         // k 512..1023 : h1 prev
    bf16x8 ah = *(const bf16x8*)(pah + (ks-16)*32);
    bf16x8 al = *(const bf16x8*)(pal + (ks-16)*32);
    #pragma unroll
    for (int q=0;q<4;q++){
      bf16x8 bh = *(const bf16x8*)(pb[q]   + ks*512);
      bf16x8 bl = *(const bf16x8*)(pb[q+4] + ks*512);
      acc[q] = __builtin_amdgcn_mfma_f32_16x16x32_bf16(ah, bh, acc[q], 0,0,0);
      acc[q] = __builtin_amdgcn_mfma_f32_16x16x32_bf16(al, bh, acc[q], 0,0,0);
      acc[q] = __builtin_amdgcn_mfma_f32_16x16x32_bf16(ah, bl, acc[q], 0,0,0);
    }
  }
  const int u = ut*16 + lo16;
  const int r0 = e0 + wm*16 + kgrp*4;
  const float b0 = bias[u], b1 = bias[512+u], b2 = bias[1024+u], b3 = bias[1536+u];
  #pragma unroll
  for (int r=0;r<4;r++){
    const int e = r0 + r;
    float zi = acc[0][r] + b0;
    float zf = acc[1][r] + b1;
    float zg = acc[2][r] + b2;
    float zo = acc[3][r] + b3;
    const size_t idx = (size_t)e*512 + u;
    float c = sigf(zf)*cst[idx] + sigf(zi)*tanhf(zg);
    float h = sigf(zo)*tanhf(c);
    cst[idx] = c;
    unsigned short hb = f2bf(h);
    hoh[idx] = hb;
    hol[idx] = f2bf(h - bf2f(hb));
  }
}

// logits + argmax from bf16 hi/lo h1: one wave per batch elem
__global__ void dec_out(const unsigned short* __restrict__ h1h,
                        const unsigned short* __restrict__ h1l,
                        const float* __restrict__ outW,
                        const float* __restrict__ outb,
                        float* __restrict__ out,
                        int* __restrict__ tok, int t){
  const int lane = threadIdx.x & 63;
  const int e = blockIdx.x*4 + (threadIdx.x >> 6);
  const unsigned short* hh = h1h + (size_t)e*512;
  const unsigned short* hl = h1l + (size_t)e*512;
  float s0=0,s1=0,s2=0,s3=0,s4=0;
  for (int k=lane;k<512;k+=64){
    float hv = bf2f(hh[k]) + bf2f(hl[k]);
    s0 += hv*outW[k];
    s1 += hv*outW[512+k];
    s2 += hv*outW[1024+k];
    s3 += hv*outW[1536+k];
    s4 += hv*outW[2048+k];
  }
  #pragma unroll
  for (int off=32; off>0; off>>=1){
    s0 += __shfl_down(s0, off);
    s1 += __shfl_down(s1, off);
    s2 += __shfl_down(s2, off);
    s3 += __shfl_down(s3, off);
    s4 += __shfl_down(s4, off);
  }
  if (lane==0){
    float l[5] = { s0+outb[0], s1+outb[1], s2+outb[2], s3+outb[3], s4+outb[4] };
    float* op = out + ((size_t)e*TDEC + t)*5;
    float best = l[0]; int bi = 0;
    op[0] = l[0];
    #pragma unroll
    for (int v=1;v<5;v++){
      op[v] = l[v];
      if (l[v] > best){ best = l[v]; bi = v; }  // first-max, matches jnp.argmax
    }
    tok[e] = bi;
  }
}

extern "C" void kernel_launch(void* const* d_in, const int* in_sizes, int n_in,
                              void* d_out, int out_size, void* d_ws, size_t ws_size,
                              hipStream_t stream){
  (void)in_sizes; (void)n_in; (void)out_size;
  const int*   leftc    = (const int*)d_in[0];
  const int*   rightc   = (const int*)d_in[1];
  const float* emb      = (const float*)d_in[3];
  const float* ctx0_Wih = (const float*)d_in[4];
  const float* ctx0_Whh = (const float*)d_in[5];
  const float* ctx0_b   = (const float*)d_in[6];
  const float* ctx1_Wih = (const float*)d_in[7];
  const float* ctx1_Whh = (const float*)d_in[8];
  const float* ctx1_b   = (const float*)d_in[9];
  const float* gen0_Wih = (const float*)d_in[10];
  const float* gen0_Whh = (const float*)d_in[11];
  const float* gen0_b   = (const float*)d_in[12];
  const float* gen1_Wih = (const float*)d_in[13];
  const float* gen1_Whh = (const float*)d_in[14];
  const float* gen1_b   = (const float*)d_in[15];
  const float* out_W    = (const float*)d_in[16];
  const float* out_b    = (const float*)d_in[17];
  float* out = (float*)d_out;

  char* p = (char*)d_ws;
  auto carve = [&](size_t nfloats)->float*{
    float* r = (float*)p;
    p += ((nfloats*sizeof(float) + 255) & ~(size_t)255);
    return r;
  };
  auto carveu = [&](size_t nush)->unsigned short*{
    return (unsigned short*)carve((nush + 1)/2);
  };
  float* c0WhhT = carve((size_t)2*256*1024);
  float* c1WihT = carve((size_t)2*512*1024);
  float* c1WhhT = carve((size_t)2*256*1024);
  float* ectx0  = carve(2*5*1024);
  float* egen0  = carve(5*2048);
  float* leftF  = carve((size_t)BATCH*HG);
  float* rightF = carve((size_t)BATCH*HG);
  float* c0s    = carve((size_t)BATCH*HG);
  float* c1s    = carve((size_t)BATCH*HG);
  unsigned short* pk0h = carveu((size_t)2048*512);
  unsigned short* pk0l = carveu((size_t)2048*512);
  unsigned short* pk1h = carveu((size_t)2048*1024);
  unsigned short* pk1l = carveu((size_t)2048*1024);
  unsigned short* h0ha = carveu((size_t)BATCH*HG);
  unsigned short* h0la = carveu((size_t)BATCH*HG);
  unsigned short* h0hb = carveu((size_t)BATCH*HG);
  unsigned short* h0lb = carveu((size_t)BATCH*HG);
  unsigned short* h1ha = carveu((size_t)BATCH*HG);
  unsigned short* h1la = carveu((size_t)BATCH*HG);
  unsigned short* h1hb = carveu((size_t)BATCH*HG);
  unsigned short* h1lb = carveu((size_t)BATCH*HG);
  int*   tok    = (int*)carve(BATCH);
  float* y0     = carve((size_t)L_SEQ*BATCH*512);   // 210 MB, largest last
  if ((size_t)(p - (char*)d_ws) > ws_size) return;  // insufficient workspace -> loud fail

  auto T = [&](const float* s, float* d, int J, int K){
    int n = J*K;
    transpose_k<<<(n+255)/256, 256, 0, stream>>>(s, d, J, K);
  };
  T(ctx0_Whh,          c0WhhT,          1024, 256);
  T(ctx0_Whh+1024*256, c0WhhT+256*1024, 1024, 256);
  T(ctx1_Wih,          c1WihT,          1024, 512);
  T(ctx1_Wih+1024*512, c1WihT+512*1024, 1024, 512);
  T(ctx1_Whh,          c1WhhT,          1024, 256);
  T(ctx1_Whh+1024*256, c1WhhT+256*1024, 1024, 256);

  // decoder weight packs: (G/16)*(K/32)*64 = 131072 threads each
  pack_w<<<512, 256, 0, stream>>>(gen0_Whh, 2048, 512, 16,  0, pk0h, pk0l);
  pack_w<<<512, 256, 0, stream>>>(gen1_Wih, 2048, 512, 32,  0, pk1h, pk1l);
  pack_w<<<512, 256, 0, stream>>>(gen1_Whh, 2048, 512, 32, 16, pk1h, pk1l);

  embprep<<<(20480+255)/256, 256, 0, stream>>>(emb, ctx0_Wih, ctx0_b,
                                               gen0_Wih, gen0_b, ectx0, egen0);

  // left encode (finals at t=99), then right (finals at t=0); y0 reused
  ctx_l0<<<dim3(128,2), 512, 0, stream>>>(leftc, ectx0, c0WhhT, y0);
  ctx_l1<<<256, 512, 0, stream>>>(y0, c1WihT, c1WhhT, ctx1_b, leftF, L_SEQ-1);
  ctx_l0<<<dim3(128,2), 512, 0, stream>>>(rightc, ectx0, c0WhhT, y0);
  ctx_l1<<<256, 512, 0, stream>>>(y0, c1WihT, c1WhhT, ctx1_b, rightF, 0);

  combine_init2<<<(BATCH*HG+255)/256, 256, 0, stream>>>(leftF, rightF,
                                                        h0ha, h0la, h1ha, h1la,
                                                        c0s, c1s, tok);

  for (int t=0;t<TDEC;t++){
    unsigned short* h0ih = (t&1)? h0hb : h0ha;
    unsigned short* h0il = (t&1)? h0lb : h0la;
    unsigned short* h0oh = (t&1)? h0ha : h0hb;
    unsigned short* h0ol = (t&1)? h0la : h0lb;
    unsigned short* h1ih = (t&1)? h1hb : h1ha;
    unsigned short* h1il = (t&1)? h1lb : h1la;
    unsigned short* h1oh = (t&1)? h1ha : h1hb;
    unsigned short* h1ol = (t&1)? h1la : h1lb;
    dec_l0_mfma<<<256, 512, 0, stream>>>(tok, egen0, pk0h, pk0l,
                                         h0ih, h0il, h0oh, h0ol, c0s);
    dec_l1_mfma<<<256, 512, 0, stream>>>(h0oh, h0ol, pk1h, pk1l, gen1_b,
                                         h1ih, h1il, h1oh, h1ol, c1s);
    dec_out<<<256, 256, 0, stream>>>(h1oh, h1ol, out_W, out_b, out, tok, t);
  }
}

// Round 2
// 23132.515 us; speedup vs baseline: 3.1313x; 1.4657x over previous
//
#include <hip/hip_runtime.h>

// LSTMGapFiller R3: context LSTMs -> bf16x3 split MFMA (like decoder in R2).
// Per (dir, 16-row batch slice) self-contained block, h/c resident in LDS for
// all 100 steps; A-frags via XOR-swizzled LDS (conflict-free ds_read_b128);
// y0 inter-layer tensor stored as bf16 hi/lo; weights packed fragment-linear.
// Decoder unchanged from R2 (bf16x3 MFMA, passed at absmax 9.8e-4).

#define L_SEQ 100
#define BATCH 1024
#define HCTX 256
#define HG 512
#define TDEC 256

typedef __attribute__((ext_vector_type(8))) short bf16x8;
typedef __attribute__((ext_vector_type(4))) float f32x4;

__device__ __forceinline__ float sigf(float x){ return 1.0f/(1.0f+expf(-x)); }
__device__ __forceinline__ unsigned short f2bf(float x){
  unsigned int u = __float_as_uint(x);
  return (unsigned short)((u + 0x7fffu + ((u>>16)&1u)) >> 16);   // RNE
}
__device__ __forceinline__ float bf2f(unsigned short h){
  return __uint_as_float(((unsigned int)h)<<16);
}

// Pack W[G][K] (fp32, row-major) into MFMA-fragment-linear bf16 hi/lo.
// Element (gt, kt, lane, j) = W[gt*16 + (lane&15)][kt*32 + (lane>>4)*8 + j],
// stored at ((gt*KTtot + kt0+ktl)*64 + lane)*8 + j  -> per-lane 16B contiguous.
__global__ void pack_w(const float* __restrict__ W, int G, int K, int KTtot, int kt0,
                       unsigned short* __restrict__ hi, unsigned short* __restrict__ lo){
  int idx = blockIdx.x*blockDim.x + threadIdx.x;
  int kt_n = K/32;
  int total = (G/16)*kt_n*64;
  if (idx >= total) return;
  int lane = idx & 63;
  int ktl = (idx>>6) % kt_n;
  int gt  = (idx>>6) / kt_n;
  int g = gt*16 + (lane & 15);
  int k = ktl*32 + (lane>>4)*8;
  const float* src = W + (size_t)g*K + k;
  size_t dst = (((size_t)gt*KTtot + (kt0 + ktl))*64 + lane)*8;
  #pragma unroll
  for (int j=0;j<8;j++){
    float x = src[j];
    unsigned short h = f2bf(x);
    hi[dst+j] = h;
    lo[dst+j] = f2bf(x - bf2f(h));
  }
}

// precompute embedding projections (vocab=5):
// ectx0[d][v][j] = ctx0_b[d][j] + emb[v] . ctx0_Wih[d][j]   (j<1024)
// egen0[v][j]    = gen0_b[j]    + emb[v] . gen0_Wih[j]      (j<2048)
__global__ void embprep(const float* __restrict__ emb,
                        const float* __restrict__ c0Wih, const float* __restrict__ c0b,
                        const float* __restrict__ g0Wih, const float* __restrict__ g0b,
                        float* __restrict__ ectx0, float* __restrict__ egen0){
  int idx = blockIdx.x*blockDim.x + threadIdx.x;
  if (idx < 2*5*1024){
    int d = idx / 5120;
    int v = (idx / 1024) % 5;
    int j = idx % 1024;
    const float* w = c0Wih + ((size_t)d*1024 + j)*64;
    const float* e = emb + v*64;
    float s = c0b[d*1024 + j];
    #pragma unroll
    for (int k=0;k<64;k++) s += e[k]*w[k];
    ectx0[idx] = s;
  } else if (idx < 2*5*1024 + 5*2048){
    int i2 = idx - 10240;
    int v = i2 / 2048;
    int j = i2 % 2048;
    const float* w = g0Wih + (size_t)j*64;
    const float* e = emb + v*64;
    float s = g0b[j];
    #pragma unroll
    for (int k=0;k<64;k++) s += e[k]*w[k];
    egen0[i2] = s;
  }
}

// ---------------- context layer 0 (MFMA) ----------------
// 128 blocks x 512 thr (8 waves). Block = (dir, 16 batch rows), all 256 units.
// Wave w owns units [w*32, w*32+32) x 4 gates = 8 col-tiles. KT=8 (K=256).
// dir = (id>>2)&1 -> dir0 on XCDs 0-3, dir1 on 4-7 (weights L2-resident).
__global__ void __launch_bounds__(512,1) ctx_l0_mfma(
    const int* __restrict__ toks,
    const float* __restrict__ ectx0,
    const unsigned short* __restrict__ wh, const unsigned short* __restrict__ wl,
    unsigned short* __restrict__ y0h, unsigned short* __restrict__ y0l)
{
  const int id  = blockIdx.x;
  const int dir = (id >> 2) & 1;
  const int bx  = ((id >> 3) << 2) | (id & 3);
  const int e0  = bx * 16;
  const int lane = threadIdx.x & 63;
  const int w    = threadIdx.x >> 6;
  const int lo16 = lane & 15, kgrp = lane >> 4;

  __shared__ unsigned short hsh[16*256];
  __shared__ unsigned short hsl[16*256];
  __shared__ float cs[16*256];
  for (int i=threadIdx.x;i<16*256;i+=512){ hsh[i]=0; hsl[i]=0; cs[i]=0.f; }
  __syncthreads();

  const unsigned short* pbh[4][2];
  const unsigned short* pbl[4][2];
  #pragma unroll
  for (int g=0;g<4;g++){
    #pragma unroll
    for (int st=0;st<2;st++){
      int ct = g*16 + w*2 + st;                       // col-tile 0..63
      size_t off = (size_t)dir*1024*256 + ((size_t)(ct*8)*64 + lane)*8;
      pbh[g][st] = wh + off; pbl[g][st] = wl + off;
    }
  }
  const unsigned aoff0 = (unsigned)(lo16*512 + kgrp*16);
  const unsigned axor  = ((unsigned)(lo16 & 7)) << 4;

  for (int s=0;s<L_SEQ;s++){
    const int t = dir ? (L_SEQ-1-s) : s;
    f32x4 zero = {0.f,0.f,0.f,0.f};
    f32x4 acc[4][2];
    #pragma unroll
    for (int g=0;g<4;g++){
      #pragma unroll
      for (int st=0;st<2;st++) acc[g][st] = zero;
    }
    #pragma unroll 2
    for (int kt=0;kt<8;kt++){
      unsigned ao = (aoff0 + kt*64) ^ axor;
      bf16x8 ah = *(const bf16x8*)((const char*)hsh + ao);
      bf16x8 al = *(const bf16x8*)((const char*)hsl + ao);
      #pragma unroll
      for (int g=0;g<4;g++){
        #pragma unroll
        for (int st=0;st<2;st++){
          bf16x8 bh = *(const bf16x8*)(pbh[g][st] + (size_t)kt*512);
          bf16x8 bl = *(const bf16x8*)(pbl[g][st] + (size_t)kt*512);
          acc[g][st] = __builtin_amdgcn_mfma_f32_16x16x32_bf16(ah,bh,acc[g][st],0,0,0);
          acc[g][st] = __builtin_amdgcn_mfma_f32_16x16x32_bf16(al,bh,acc[g][st],0,0,0);
          acc[g][st] = __builtin_amdgcn_mfma_f32_16x16x32_bf16(ah,bl,acc[g][st],0,0,0);
        }
      }
    }
    __syncthreads();                       // all reads of hs done
    int tkr[4];
    #pragma unroll
    for (int r=0;r<4;r++) tkr[r] = toks[(e0 + kgrp*4 + r)*L_SEQ + t];
    #pragma unroll
    for (int st=0;st<2;st++){
      const int unit = w*32 + st*16 + lo16;
      #pragma unroll
      for (int r=0;r<4;r++){
        const int row = kgrp*4 + r;
        const int e = e0 + row;
        const float* ep = ectx0 + ((size_t)(dir*5 + tkr[r]))*1024 + unit;
        float zi = acc[0][st][r] + ep[0];
        float zf = acc[1][st][r] + ep[256];
        float zg = acc[2][st][r] + ep[512];
        float zo = acc[3][st][r] + ep[768];
        int ci = row*256 + unit;
        float c = sigf(zf)*cs[ci] + sigf(zi)*tanhf(zg);
        float h = sigf(zo)*tanhf(c);
        cs[ci] = c;
        unsigned short hb = f2bf(h), lb = f2bf(h - bf2f(hb));
        unsigned hoff = ((unsigned)(row*512 + unit*2)) ^ (((unsigned)(row & 7)) << 4);
        *(unsigned short*)((char*)hsh + hoff) = hb;
        *(unsigned short*)((char*)hsl + hoff) = lb;
        size_t yo = ((size_t)t*BATCH + e)*512 + dir*256 + unit;
        y0h[yo] = hb; y0l[yo] = lb;
      }
    }
    __syncthreads();                       // new hs visible
  }
}

// ---------------- context layer 1 (MFMA) ----------------
// Same geometry; K = 512 (x from y0) + 256 (h) = 768, KT=24.
__global__ void __launch_bounds__(512,1) ctx_l1_mfma(
    const unsigned short* __restrict__ y0h, const unsigned short* __restrict__ y0l,
    const unsigned short* __restrict__ wh, const unsigned short* __restrict__ wl,
    const float* __restrict__ bias,
    float* __restrict__ finals, int t_store)
{
  const int id  = blockIdx.x;
  const int dir = (id >> 2) & 1;
  const int bx  = ((id >> 3) << 2) | (id & 3);
  const int e0  = bx * 16;
  const int lane = threadIdx.x & 63;
  const int w    = threadIdx.x >> 6;
  const int lo16 = lane & 15, kgrp = lane >> 4;

  __shared__ unsigned short xsh[16*512];
  __shared__ unsigned short xsl[16*512];
  __shared__ unsigned short hsh[16*256];
  __shared__ unsigned short hsl[16*256];
  __shared__ float cs[16*256];
  for (int i=threadIdx.x;i<16*256;i+=512){ hsh[i]=0; hsl[i]=0; cs[i]=0.f; }

  float bb[4][2];
  #pragma unroll
  for (int g=0;g<4;g++){
    #pragma unroll
    for (int st=0;st<2;st++)
      bb[g][st] = bias[dir*1024 + g*256 + w*32 + st*16 + lo16];
  }
  const unsigned short* pbh[4][2];
  const unsigned short* pbl[4][2];
  #pragma unroll
  for (int g=0;g<4;g++){
    #pragma unroll
    for (int st=0;st<2;st++){
      int ct = g*16 + w*2 + st;
      size_t off = (size_t)dir*1024*768 + ((size_t)(ct*24)*64 + lane)*8;
      pbh[g][st] = wh + off; pbl[g][st] = wl + off;
    }
  }
  const unsigned axor = ((unsigned)(lo16 & 7)) << 4;
  __syncthreads();

  for (int s=0;s<L_SEQ;s++){
    const int t = dir ? (L_SEQ-1-s) : s;
    // stage x = y0[t] rows e0..e0+15 into swizzled LDS (16B chunks)
    #pragma unroll
    for (int cc=0; cc<2; cc++){
      int ci = threadIdx.x + cc*512;       // 0..1023 chunk id
      int row = ci >> 6, cr = ci & 63;
      const unsigned short* srcbase = y0h + ((size_t)t*BATCH + e0 + row)*512 + cr*8;
      const unsigned short* srcbasel = y0l + ((size_t)t*BATCH + e0 + row)*512 + cr*8;
      uint4 vh = *(const uint4*)srcbase;
      uint4 vl = *(const uint4*)srcbasel;
      unsigned xo = ((unsigned)(row*1024 + cr*16)) ^ (((unsigned)(row & 7)) << 4);
      *(uint4*)((char*)xsh + xo) = vh;
      *(uint4*)((char*)xsl + xo) = vl;
    }
    __syncthreads();                       // x staged
    f32x4 zero = {0.f,0.f,0.f,0.f};
    f32x4 acc[4][2];
    #pragma unroll
    for (int g=0;g<4;g++){
      #pragma unroll
      for (int st=0;st<2;st++) acc[g][st] = zero;
    }
    #pragma unroll 2
    for (int kt=0;kt<16;kt++){             // x part (K 0..511)
      unsigned ao = ((unsigned)(lo16*1024 + kt*64 + kgrp*16)) ^ axor;
      bf16x8 ah = *(const bf16x8*)((const char*)xsh + ao);
      bf16x8 al = *(const bf16x8*)((const char*)xsl + ao);
      #pragma unroll
      for (int g=0;g<4;g++){
        #pragma unroll
        for (int st=0;st<2;st++){
          bf16x8 bh = *(const bf16x8*)(pbh[g][st] + (size_t)kt*512);
          bf16x8 bl = *(const bf16x8*)(pbl[g][st] + (size_t)kt*512);
          acc[g][st] = __builtin_amdgcn_mfma_f32_16x16x32_bf16(ah,bh,acc[g][st],0,0,0);
          acc[g][st] = __builtin_amdgcn_mfma_f32_16x16x32_bf16(al,bh,acc[g][st],0,0,0);
          acc[g][st] = __builtin_amdgcn_mfma_f32_16x16x32_bf16(ah,bl,acc[g][st],0,0,0);
        }
      }
    }
    #pragma unroll 2
    for (int kt=16;kt<24;kt++){            // h part (K 512..767)
      unsigned ao = ((unsigned)(lo16*512 + (kt-16)*64 + kgrp*16)) ^ axor;
      bf16x8 ah = *(const bf16x8*)((const char*)hsh + ao);
      bf16x8 al = *(const bf16x8*)((const char*)hsl + ao);
      #pragma unroll
      for (int g=0;g<4;g++){
        #pragma unroll
        for (int st=0;st<2;st++){
          bf16x8 bh = *(const bf16x8*)(pbh[g][st] + (size_t)kt*512);
          bf16x8 bl = *(const bf16x8*)(pbl[g][st] + (size_t)kt*512);
          acc[g][st] = __builtin_amdgcn_mfma_f32_16x16x32_bf16(ah,bh,acc[g][st],0,0,0);
          acc[g][st] = __builtin_amdgcn_mfma_f32_16x16x32_bf16(al,bh,acc[g][st],0,0,0);
          acc[g][st] = __builtin_amdgcn_mfma_f32_16x16x32_bf16(ah,bl,acc[g][st],0,0,0);
        }
      }
    }
    __syncthreads();                       // reads of xs/hs done
    #pragma unroll
    for (int st=0;st<2;st++){
      const int unit = w*32 + st*16 + lo16;
      #pragma unroll
      for (int r=0;r<4;r++){
        const int row = kgrp*4 + r;
        float zi = acc[0][st][r] + bb[0][st];
        float zf = acc[1][st][r] + bb[1][st];
        float zg = acc[2][st][r] + bb[2][st];
        float zo = acc[3][st][r] + bb[3][st];
        int ci = row*256 + unit;
        float c = sigf(zf)*cs[ci] + sigf(zi)*tanhf(zg);
        float h = sigf(zo)*tanhf(c);
        cs[ci] = c;
        unsigned short hb = f2bf(h), lb = f2bf(h - bf2f(hb));
        unsigned hoff = ((unsigned)(row*512 + unit*2)) ^ (((unsigned)(row & 7)) << 4);
        *(unsigned short*)((char*)hsh + hoff) = hb;
        *(unsigned short*)((char*)hsl + hoff) = lb;
        if (t == t_store)
          finals[(size_t)(e0 + row)*512 + dir*256 + unit] = h;
      }
    }
    __syncthreads();                       // new hs visible
  }
}

__global__ void combine_init2(const float* __restrict__ lf, const float* __restrict__ rf,
                              unsigned short* __restrict__ h0h, unsigned short* __restrict__ h0l,
                              unsigned short* __restrict__ h1h, unsigned short* __restrict__ h1l,
                              float* __restrict__ c0, float* __restrict__ c1,
                              int* __restrict__ tok){
  int i = blockIdx.x*blockDim.x + threadIdx.x;
  if (i < BATCH*HG){
    float v = 0.5f*(lf[i]+rf[i]);
    unsigned short h = f2bf(v);
    unsigned short l = f2bf(v - bf2f(h));
    h0h[i]=h; h0l[i]=l; h1h[i]=h; h1l[i]=l;
    c0[i]=0.f; c1[i]=0.f;
  }
  if (i < BATCH) tok[i]=0;
}

// decoder layer 0 (MFMA): 256 blocks x 512 thr (8 waves). Block = 64 elems x 32
// units (x4 gates). Wave (wm 0..3, wu 0..1) = 1 M-tile x 4 gate col-tiles.
// by = bid%16 so same-weight-slice blocks share an XCD L2.
__global__ void __launch_bounds__(512,2) dec_l0_mfma(
    const int* __restrict__ tok,
    const float* __restrict__ egen0,
    const unsigned short* __restrict__ wh, const unsigned short* __restrict__ wl,
    const unsigned short* __restrict__ hih, const unsigned short* __restrict__ hil,
    unsigned short* __restrict__ hoh, unsigned short* __restrict__ hol,
    float* __restrict__ cst)
{
  const int bid = blockIdx.x;
  const int by = bid & 15;            // unit-group (32 units)
  const int bx = bid >> 4;            // elem-group (64 elems)
  const int e0 = bx * 64;
  const int lane = threadIdx.x & 63;
  const int w = threadIdx.x >> 6;
  const int wm = w & 3;
  const int wu = w >> 2;
  const int ut = by*2 + wu;           // global unit-tile 0..31
  const int lo16 = lane & 15;
  const int kgrp = lane >> 4;
  const int row = e0 + wm*16 + lo16;

  const unsigned short* pah = hih + (size_t)row*512 + kgrp*8;
  const unsigned short* pal = hil + (size_t)row*512 + kgrp*8;
  const unsigned short* pb[8];
  #pragma unroll
  for (int q=0;q<4;q++){
    size_t off = ((size_t)(q*32+ut)*16*64 + lane)*8;   // KT=16
    pb[q]   = wh + off;
    pb[q+4] = wl + off;
  }
  f32x4 zero = {0.f,0.f,0.f,0.f};
  f32x4 acc[4] = {zero, zero, zero, zero};
  #pragma unroll 2
  for (int ks=0; ks<16; ks++){
    bf16x8 ah = *(const bf16x8*)(pah + ks*32);
    bf16x8 al = *(const bf16x8*)(pal + ks*32);
    #pragma unroll
    for (int q=0;q<4;q++){
      bf16x8 bh = *(const bf16x8*)(pb[q]   + ks*512);
      bf16x8 bl = *(const bf16x8*)(pb[q+4] + ks*512);
      acc[q] = __builtin_amdgcn_mfma_f32_16x16x32_bf16(ah, bh, acc[q], 0,0,0);
      acc[q] = __builtin_amdgcn_mfma_f32_16x16x32_bf16(al, bh, acc[q], 0,0,0);
      acc[q] = __builtin_amdgcn_mfma_f32_16x16x32_bf16(ah, bl, acc[q], 0,0,0);
    }
  }
  const int u = ut*16 + lo16;
  const int r0 = e0 + wm*16 + kgrp*4;   // D row = 4*(lane>>4)+reg (m89 layout)
  #pragma unroll
  for (int r=0;r<4;r++){
    const int e = r0 + r;
    const int tk = tok[e];
    const float* ep = egen0 + (size_t)tk*2048 + u;
    float zi = acc[0][r] + ep[0];
    float zf = acc[1][r] + ep[512];
    float zg = acc[2][r] + ep[1024];
    float zo = acc[3][r] + ep[1536];
    const size_t idx = (size_t)e*512 + u;
    float c = sigf(zf)*cst[idx] + sigf(zi)*tanhf(zg);
    float h = sigf(zo)*tanhf(c);
    cst[idx] = c;
    unsigned short hb = f2bf(h);
    hoh[idx] = hb;
    hol[idx] = f2bf(h - bf2f(hb));
  }
}

// decoder layer 1 (MFMA): K=1024 = [x(=h0out) ; h1prev]. Same geometry, KT=32.
__global__ void __launch_bounds__(512,2) dec_l1_mfma(
    const unsigned short* __restrict__ xh, const unsigned short* __restrict__ xl,
    const unsigned short* __restrict__ wh, const unsigned short* __restrict__ wl,
    const float* __restrict__ bias,
    const unsigned short* __restrict__ hih, const unsigned short* __restrict__ hil,
    unsigned short* __restrict__ hoh, unsigned short* __restrict__ hol,
    float* __restrict__ cst)
{
  const int bid = blockIdx.x;
  const int by = bid & 15;
  const int bx = bid >> 4;
  const int e0 = bx * 64;
  const int lane = threadIdx.x & 63;
  const int w = threadIdx.x >> 6;
  const int wm = w & 3;
  const int wu = w >> 2;
  const int ut = by*2 + wu;
  const int lo16 = lane & 15;
  const int kgrp = lane >> 4;
  const int row = e0 + wm*16 + lo16;

  const unsigned short* pxh = xh  + (size_t)row*512 + kgrp*8;
  const unsigned short* pxl = xl  + (size_t)row*512 + kgrp*8;
  const unsigned short* pah = hih + (size_t)row*512 + kgrp*8;
  const unsigned short* pal = hil + (size_t)row*512 + kgrp*8;
  const unsigned short* pb[8];
  #pragma unroll
  for (int q=0;q<4;q++){
    size_t off = ((size_t)(q*32+ut)*32*64 + lane)*8;   // KT=32
    pb[q]   = wh + off;
    pb[q+4] = wl + off;
  }
  f32x4 zero = {0.f,0.f,0.f,0.f};
  f32x4 acc[4] = {zero, zero, zero, zero};
  #pragma unroll 2
  for (int ks=0; ks<16; ks++){          // k 0..511 : x
    bf16x8 ah = *(const bf16x8*)(pxh + ks*32);
    bf16x8 al = *(const bf16x8*)(pxl + ks*32);
    #pragma unroll
    for (int q=0;q<4;q++){
      bf16x8 bh = *(const bf16x8*)(pb[q]   + ks*512);
      bf16x8 bl = *(const bf16x8*)(pb[q+4] + ks*512);
      acc[q] = __builtin_amdgcn_mfma_f32_16x16x32_bf16(ah, bh, acc[q], 0,0,0);
      acc[q] = __builtin_amdgcn_mfma_f32_16x16x32_bf16(al, bh, acc[q], 0,0,0);
      acc[q] = __builtin_amdgcn_mfma_f32_16x16x32_bf16(ah, bl, acc[q], 0,0,0);
    }
  }
  #pragma unroll 2
  for (int ks=16; ks<32; ks++){         // k 512..1023 : h1 prev
    bf16x8 ah = *(const bf16x8*)(pah + (ks-16)*32);
    bf16x8 al = *(const bf16x8*)(pal + (ks-16)*32);
    #pragma unroll
    for (int q=0;q<4;q++){
      bf16x8 bh = *(const bf16x8*)(pb[q]   + ks*512);
      bf16x8 bl = *(const bf16x8*)(pb[q+4] + ks*512);
      acc[q] = __builtin_amdgcn_mfma_f32_16x16x32_bf16(ah, bh, acc[q], 0,0,0);
      acc[q] = __builtin_amdgcn_mfma_f32_16x16x32_bf16(al, bh, acc[q], 0,0,0);
      acc[q] = __builtin_amdgcn_mfma_f32_16x16x32_bf16(ah, bl, acc[q], 0,0,0);
    }
  }
  const int u = ut*16 + lo16;
  const int r0 = e0 + wm*16 + kgrp*4;
  const float b0 = bias[u], b1 = bias[512+u], b2 = bias[1024+u], b3 = bias[1536+u];
  #pragma unroll
  for (int r=0;r<4;r++){
    const int e = r0 + r;
    float zi = acc[0][r] + b0;
    float zf = acc[1][r] + b1;
    float zg = acc[2][r] + b2;
    float zo = acc[3][r] + b3;
    const size_t idx = (size_t)e*512 + u;
    float c = sigf(zf)*cst[idx] + sigf(zi)*tanhf(zg);
    float h = sigf(zo)*tanhf(c);
    cst[idx] = c;
    unsigned short hb = f2bf(h);
    hoh[idx] = hb;
    hol[idx] = f2bf(h - bf2f(hb));
  }
}

// logits + argmax from bf16 hi/lo h1: one wave per batch elem
__global__ void dec_out(const unsigned short* __restrict__ h1h,
                        const unsigned short* __restrict__ h1l,
                        const float* __restrict__ outW,
                        const float* __restrict__ outb,
                        float* __restrict__ out,
                        int* __restrict__ tok, int t){
  const int lane = threadIdx.x & 63;
  const int e = blockIdx.x*4 + (threadIdx.x >> 6);
  const unsigned short* hh = h1h + (size_t)e*512;
  const unsigned short* hl = h1l + (size_t)e*512;
  float s0=0,s1=0,s2=0,s3=0,s4=0;
  for (int k=lane;k<512;k+=64){
    float hv = bf2f(hh[k]) + bf2f(hl[k]);
    s0 += hv*outW[k];
    s1 += hv*outW[512+k];
    s2 += hv*outW[1024+k];
    s3 += hv*outW[1536+k];
    s4 += hv*outW[2048+k];
  }
  #pragma unroll
  for (int off=32; off>0; off>>=1){
    s0 += __shfl_down(s0, off);
    s1 += __shfl_down(s1, off);
    s2 += __shfl_down(s2, off);
    s3 += __shfl_down(s3, off);
    s4 += __shfl_down(s4, off);
  }
  if (lane==0){
    float l[5] = { s0+outb[0], s1+outb[1], s2+outb[2], s3+outb[3], s4+outb[4] };
    float* op = out + ((size_t)e*TDEC + t)*5;
    float best = l[0]; int bi = 0;
    op[0] = l[0];
    #pragma unroll
    for (int v=1;v<5;v++){
      op[v] = l[v];
      if (l[v] > best){ best = l[v]; bi = v; }  // first-max, matches jnp.argmax
    }
    tok[e] = bi;
  }
}

extern "C" void kernel_launch(void* const* d_in, const int* in_sizes, int n_in,
                              void* d_out, int out_size, void* d_ws, size_t ws_size,
                              hipStream_t stream){
  (void)in_sizes; (void)n_in; (void)out_size;
  const int*   leftc    = (const int*)d_in[0];
  const int*   rightc   = (const int*)d_in[1];
  const float* emb      = (const float*)d_in[3];
  const float* ctx0_Wih = (const float*)d_in[4];
  const float* ctx0_Whh = (const float*)d_in[5];
  const float* ctx0_b   = (const float*)d_in[6];
  const float* ctx1_Wih = (const float*)d_in[7];
  const float* ctx1_Whh = (const float*)d_in[8];
  const float* ctx1_b   = (const float*)d_in[9];
  const float* gen0_Wih = (const float*)d_in[10];
  const float* gen0_Whh = (const float*)d_in[11];
  const float* gen0_b   = (const float*)d_in[12];
  const float* gen1_Wih = (const float*)d_in[13];
  const float* gen1_Whh = (const float*)d_in[14];
  const float* gen1_b   = (const float*)d_in[15];
  const float* out_W    = (const float*)d_in[16];
  const float* out_b    = (const float*)d_in[17];
  float* out = (float*)d_out;

  char* p = (char*)d_ws;
  auto carve = [&](size_t nfloats)->float*{
    float* r = (float*)p;
    p += ((nfloats*sizeof(float) + 255) & ~(size_t)255);
    return r;
  };
  auto carveu = [&](size_t nush)->unsigned short*{
    return (unsigned short*)carve((nush + 1)/2);
  };
  float* ectx0  = carve(2*5*1024);
  float* egen0  = carve(5*2048);
  float* leftF  = carve((size_t)BATCH*HG);
  float* rightF = carve((size_t)BATCH*HG);
  float* c0s    = carve((size_t)BATCH*HG);
  float* c1s    = carve((size_t)BATCH*HG);
  unsigned short* c0pkh = carveu((size_t)2*1024*256);
  unsigned short* c0pkl = carveu((size_t)2*1024*256);
  unsigned short* c1pkh = carveu((size_t)2*1024*768);
  unsigned short* c1pkl = carveu((size_t)2*1024*768);
  unsigned short* pk0h = carveu((size_t)2048*512);
  unsigned short* pk0l = carveu((size_t)2048*512);
  unsigned short* pk1h = carveu((size_t)2048*1024);
  unsigned short* pk1l = carveu((size_t)2048*1024);
  unsigned short* h0ha = carveu((size_t)BATCH*HG);
  unsigned short* h0la = carveu((size_t)BATCH*HG);
  unsigned short* h0hb = carveu((size_t)BATCH*HG);
  unsigned short* h0lb = carveu((size_t)BATCH*HG);
  unsigned short* h1ha = carveu((size_t)BATCH*HG);
  unsigned short* h1la = carveu((size_t)BATCH*HG);
  unsigned short* h1hb = carveu((size_t)BATCH*HG);
  unsigned short* h1lb = carveu((size_t)BATCH*HG);
  int*   tok    = (int*)carve(BATCH);
  unsigned short* y0h = carveu((size_t)L_SEQ*BATCH*512);   // 105 MB
  unsigned short* y0l = carveu((size_t)L_SEQ*BATCH*512);   // 105 MB
  if ((size_t)(p - (char*)d_ws) > ws_size) return;  // insufficient workspace -> loud fail

  // weight packs (fragment-linear bf16 hi/lo)
  for (int d=0; d<2; d++){
    pack_w<<<128, 256, 0, stream>>>(ctx0_Whh + (size_t)d*1024*256, 1024, 256, 8, 0,
                                    c0pkh + (size_t)d*1024*256/ (size_t)1 * 0 + (size_t)d*262144,
                                    c0pkl + (size_t)d*262144);
    pack_w<<<256, 256, 0, stream>>>(ctx1_Wih + (size_t)d*1024*512, 1024, 512, 24, 0,
                                    c1pkh + (size_t)d*786432, c1pkl + (size_t)d*786432);
    pack_w<<<128, 256, 0, stream>>>(ctx1_Whh + (size_t)d*1024*256, 1024, 256, 24, 16,
                                    c1pkh + (size_t)d*786432, c1pkl + (size_t)d*786432);
  }
  pack_w<<<512, 256, 0, stream>>>(gen0_Whh, 2048, 512, 16,  0, pk0h, pk0l);
  pack_w<<<512, 256, 0, stream>>>(gen1_Wih, 2048, 512, 32,  0, pk1h, pk1l);
  pack_w<<<512, 256, 0, stream>>>(gen1_Whh, 2048, 512, 32, 16, pk1h, pk1l);

  embprep<<<(20480+255)/256, 256, 0, stream>>>(emb, ctx0_Wih, ctx0_b,
                                               gen0_Wih, gen0_b, ectx0, egen0);

  // left encode (finals at t=99), then right (finals at t=0); y0 reused
  ctx_l0_mfma<<<128, 512, 0, stream>>>(leftc, ectx0, c0pkh, c0pkl, y0h, y0l);
  ctx_l1_mfma<<<128, 512, 0, stream>>>(y0h, y0l, c1pkh, c1pkl, ctx1_b, leftF, L_SEQ-1);
  ctx_l0_mfma<<<128, 512, 0, stream>>>(rightc, ectx0, c0pkh, c0pkl, y0h, y0l);
  ctx_l1_mfma<<<128, 512, 0, stream>>>(y0h, y0l, c1pkh, c1pkl, ctx1_b, rightF, 0);

  combine_init2<<<(BATCH*HG+255)/256, 256, 0, stream>>>(leftF, rightF,
                                                        h0ha, h0la, h1ha, h1la,
                                                        c0s, c1s, tok);

  for (int t=0;t<TDEC;t++){
    unsigned short* h0ih = (t&1)? h0hb : h0ha;
    unsigned short* h0il = (t&1)? h0lb : h0la;
    unsigned short* h0oh = (t&1)? h0ha : h0hb;
    unsigned short* h0ol = (t&1)? h0la : h0lb;
    unsigned short* h1ih = (t&1)? h1hb : h1ha;
    unsigned short* h1il = (t&1)? h1lb : h1la;
    unsigned short* h1oh = (t&1)? h1ha : h1hb;
    unsigned short* h1ol = (t&1)? h1la : h1lb;
    dec_l0_mfma<<<256, 512, 0, stream>>>(tok, egen0, pk0h, pk0l,
                                         h0ih, h0il, h0oh, h0ol, c0s);
    dec_l1_mfma<<<256, 512, 0, stream>>>(h0oh, h0ol, pk1h, pk1l, gen1_b,
                                         h1ih, h1il, h1oh, h1ol, c1s);
    dec_out<<<256, 256, 0, stream>>>(h1oh, h1ol, out_W, out_b, out, tok, t);
  }
}